// Round 12
// baseline (843.402 us; speedup 1.0000x reference)
//
#include <hip/hip_runtime.h>
#include <hip/hip_bf16.h>

// ---------------------------------------------------------------------------
// WeightOnlyLinear: y = x @ dequant4(qweight, scales, qzeros) + bias
//   x (8192,4096) fp32 | scales (32,12288) | bias (12288) | qweight (512,12288)
//   qzeros (32,1536) | out (8192,12288) fp32
// R12 (= R11 with macro fix): pre-tiled fragment-major operands, 32x32x16
//   MFMA, x4-unrolled phases; B operand BYPASSES LDS (4-deep VGPR ring,
//   inline-asm global_load_dwordx4, loaded 2 phases ahead); A in LDS ring-4
//   (16KB slots, 64KB). LDS/phase 128->80KB. Ledger: 6 VMEM/body (2 A-stage
//   + 4 B-load), entry vmcnt(6); tail 6/6/4/0; B regs tied into waitcnt asm.
// ---------------------------------------------------------------------------

typedef __attribute__((ext_vector_type(8))) short short8;
typedef __attribute__((ext_vector_type(4))) float f32x4;
typedef __attribute__((ext_vector_type(16))) float f32x16;

__device__ __forceinline__ short f2bf(float f) {
  unsigned u = __float_as_uint(f);
  u += 0x7fffu + ((u >> 16) & 1u);
  return (short)(u >> 16);
}

__device__ __forceinline__ void gload_lds16(const void* g, void* l) {
  __builtin_amdgcn_global_load_lds(
      (const __attribute__((address_space(1))) void*)g,
      (__attribute__((address_space(3))) void*)l,
      16, 0, 0);
}

__device__ __forceinline__ void bar() {
  asm volatile("" ::: "memory");
  __builtin_amdgcn_s_barrier();
  asm volatile("" ::: "memory");
}

// ---------------------------------------------------------------------------
// Pass 1: dequant qweight -> B' fragment-major tiles.
// Tile (nb256, h32) = 16KB; chunk c = cb*128 + kh*64 + kq2*32 + lane31.
// ---------------------------------------------------------------------------
__global__ __launch_bounds__(256) void dequant_tile_kernel(
    const int* __restrict__ qweight, const int* __restrict__ qzeros,
    const float* __restrict__ scales, short* __restrict__ Bt,
    int N, int K) {
  const int kt = K >> 5;
  const int bx = blockIdx.x;
  const int nb = bx / kt, h = bx - nb * kt;
  const int t = threadIdx.x;
  const int n = nb * 256 + t;
  const int g = h >> 2;
  const float sc = scales[(size_t)g * N + n];
  const int zw = qzeros[(size_t)g * (N >> 3) + (n >> 3)];
  const float zs = -(float)(((zw >> ((n & 7) * 4)) & 15) + 1) * sc;
  char* dst = (char*)Bt + (size_t)bx * 16384;
#pragma unroll
  for (int kw = 0; kw < 4; ++kw) {
    const int w = qweight[(size_t)(h * 4 + kw) * N + n];
    short8 v;
#pragma unroll
    for (int e = 0; e < 8; ++e)
      v[e] = f2bf(fmaf((float)((w >> (4 * e)) & 15), sc, zs));
    const int c = ((t >> 5) << 7) + ((kw >> 1) << 6) + ((kw & 1) << 5) + (t & 31);
    *(short8*)(dst + c * 16) = v;
  }
}

// ---------------------------------------------------------------------------
// Pass 2: x fp32 -> A' fragment-major tiles (same chunk mapping).
// ---------------------------------------------------------------------------
__global__ __launch_bounds__(256) void cvt_tile_kernel(
    const float* __restrict__ x, short* __restrict__ xb, int K) {
  const int kt = K >> 5;
  const int bx = blockIdx.x;
  const int mb = bx / kt, h = bx - mb * kt;
  const float* xs = x + (size_t)mb * 256 * K + h * 32;
  char* dst = (char*)xb + (size_t)bx * 16384;
#pragma unroll
  for (int p = 0; p < 4; ++p) {
    const int t2 = p * 256 + threadIdx.x;
    const int row = t2 >> 2, kq = t2 & 3;
    const float* s = xs + (size_t)row * K + kq * 8;
    float4 f0 = *(const float4*)s;
    float4 f1 = *(const float4*)(s + 4);
    short8 v;
    v[0] = f2bf(f0.x); v[1] = f2bf(f0.y); v[2] = f2bf(f0.z); v[3] = f2bf(f0.w);
    v[4] = f2bf(f1.x); v[5] = f2bf(f1.y); v[6] = f2bf(f1.z); v[7] = f2bf(f1.w);
    const int c = ((row >> 5) << 7) + ((kq >> 1) << 6) + ((kq & 1) << 5) + (row & 31);
    *(short8*)(dst + c * 16) = v;
  }
}

// ---------------------------------------------------------------------------
// Pass 3: 256x256 GEMM, 512 threads = 8 waves (2M x 4N), wave 128x64.
// MFMA 32x32x16; wave tile 4x2 frags. A: LDS ring-4 x 16KB; B: VGPR ring-4.
// Body q (x4 unrolled, SL = q&3):
//   waitcnt vmcnt(6) [ties bs[SL] regs]; s_barrier;
//   8x ds_read_b128 A frags (slot SL);
//   stage A(q+3) [2 gload_lds]; load B(q+2) -> bs[(SL+2)&3] [4 asm gloads];
//   16 MFMA (a[i][kh] x bs[SL][j*2+kh]).
// Ledger: 6 VMEM/body, order A-stage then B-load; entry vm6 => A(q),A(q+1)
// in LDS, B(q) in regs. Tail: vm6 / vm6 / vm4 / vm0.
// ---------------------------------------------------------------------------
#define GBM 256
#define GBN 256

__global__ __launch_bounds__(512, 2) void gemm256_kernel(
    const short* __restrict__ At, const short* __restrict__ Bt,
    const float* __restrict__ bias, float* __restrict__ C,
    int M, int N, int K) {
  __shared__ __align__(16) char lds[4][16384];
  const int tid = threadIdx.x;
  const int nbx = N / GBN;
  const int nwg = gridDim.x;
  int bid = blockIdx.x;
  if ((nwg & 7) == 0) bid = (bid & 7) * (nwg >> 3) + (bid >> 3);  // T1
  const int mb = bid / nbx;
  const int nb = bid % nbx;
  const int bm = mb * GBM, bn = nb * GBN;

  const int wid = tid >> 6, lane = tid & 63;
  const int wr = wid >> 2, wc = wid & 3;  // 2x4 wave grid
  const int l31 = lane & 31;
  const int lq2 = lane >> 5;

  const int P = K >> 5;  // 32-K phases; P % 4 == 0, P >= 8 (K % 256 == 0)

  char* lb = &lds[0][0];

  // A ds_read base: + SL*16384 + i*2048 + kh*1024 (all immediates)
  const char* aBase = lb + wr * 8192 + lane * 16;

  // A staging: thread stages chunks {tid, tid+512} of the 16KB K-half tile
  const char* pAs = (const char*)At + (size_t)mb * P * 16384 + (size_t)tid * 16;
  char* dstA0 = lb + tid * 16;
  char* dstA1 = dstA0 + 8192;

  // B register loads: wave's 4 fragments at cb=wc*2+j, kh -> idx*1024
  const char* pBb = (const char*)Bt + (size_t)nb * P * 16384 + wc * 4096 +
                    (size_t)lane * 16;

  short8 bs[4][4];  // [set][j*2+kh], statically indexed everywhere

// SRC = pointer to this thread's chunk of the A K-half tile
#define STAGEA(NSL, SRC)                                    \
  do {                                                      \
    gload_lds16((SRC), dstA0 + (NSL) * 16384);              \
    gload_lds16((SRC) + 8192, dstA1 + (NSL) * 16384);       \
  } while (0)

#define LOADB(SET, SRC)                                              \
  do {                                                               \
    asm volatile("global_load_dwordx4 %0, %1, off"                   \
                 : "=v"(bs[SET][0]) : "v"((SRC)));                   \
    asm volatile("global_load_dwordx4 %0, %1, off"                   \
                 : "=v"(bs[SET][1]) : "v"((SRC) + 1024));            \
    asm volatile("global_load_dwordx4 %0, %1, off"                   \
                 : "=v"(bs[SET][2]) : "v"((SRC) + 2048));            \
    asm volatile("global_load_dwordx4 %0, %1, off"                   \
                 : "=v"(bs[SET][3]) : "v"((SRC) + 3072));            \
  } while (0)

// wait vmcnt(N) and tie set SET's registers so MFMAs can't hoist above
#define WAITB(NSTR, SET)                                                  \
  asm volatile("s_waitcnt vmcnt(" NSTR ")"                                \
               : "+v"(bs[SET][0]), "+v"(bs[SET][1]), "+v"(bs[SET][2]),    \
                 "+v"(bs[SET][3])::"memory")

  f32x16 acc[4][2] = {};

#define PHASE(SL, STG, LDB, WN)                                               \
  do {                                                                        \
    WAITB(WN, SL);                                                            \
    bar();                                                                    \
    short8 a[4][2];                                                           \
    _Pragma("unroll") for (int i = 0; i < 4; ++i)                             \
        _Pragma("unroll") for (int kh = 0; kh < 2; ++kh) a[i][kh] =           \
        *(const short8*)(aBase + (SL)*16384 + i * 2048 + kh * 1024);          \
    if (STG) STAGEA(((SL) + 3) & 3, pAo + (SL) * 16384);                      \
    if (LDB) LOADB(((SL) + 2) & 3, pBo + (SL) * 16384);                       \
    __builtin_amdgcn_s_setprio(1);                                            \
    _Pragma("unroll") for (int kh = 0; kh < 2; ++kh)                          \
        _Pragma("unroll") for (int i = 0; i < 4; ++i)                         \
        _Pragma("unroll") for (int j = 0; j < 2; ++j) acc[i][j] =             \
            __builtin_amdgcn_mfma_f32_32x32x16_bf16(                          \
                a[i][kh], bs[SL][j * 2 + kh], acc[i][j], 0, 0, 0);            \
    __builtin_amdgcn_s_setprio(0);                                            \
  } while (0)

  // --- prologue: A(0),B(0),A(1),B(1),A(2)  [ledger order matters] ---
  STAGEA(0, pAs);
  LOADB(0, pBb);
  STAGEA(1, pAs + 16384);
  LOADB(1, pBb + 16384);
  STAGEA(2, pAs + 32768);

  // --- main loop: PHASE(SL) stages A(4it+3+SL), loads B(4it+2+SL) ---
  size_t pAoff = 3 * 16384, pBoff = 2 * 16384;
  const int nIt = P / 4 - 1;
  for (int it = 0; it < nIt; ++it) {
    const char* pAo = pAs + pAoff;
    const char* pBo = pBb + pBoff;
    PHASE(0, true, true, "6");
    PHASE(1, true, true, "6");
    PHASE(2, true, true, "6");
    PHASE(3, true, true, "6");
    pAoff += 65536;
    pBoff += 65536;
  }
  // --- tail: q = P-4..P-1 ---
  {
    const char* pAo = pAs + pAoff;
    const char* pBo = pBb + pBoff;
    PHASE(0, true, true, "6");    // stage A(P-1), load B(P-2)
    PHASE(1, false, true, "6");   // load B(P-1)
    PHASE(2, false, false, "4");
    PHASE(3, false, false, "0");
  }

#undef PHASE
#undef WAITB
#undef LOADB
#undef STAGEA

  // --- epilogue: C = acc + bias.
  // 32x32 C/D map: col = lane&31, row = (reg&3) + 8*(reg>>2) + 4*(lane>>5)
  const int crow0 = bm + wr * 128 + 4 * lq2;
#pragma unroll
  for (int j = 0; j < 2; ++j) {
    const int ccol = bn + wc * 64 + j * 32 + l31;
    const float bv = bias[ccol];
#pragma unroll
    for (int i = 0; i < 4; ++i) {
#pragma unroll
      for (int reg = 0; reg < 16; ++reg) {
        const int row = crow0 + i * 32 + (reg & 3) + 8 * (reg >> 2);
        C[(size_t)row * N + ccol] = acc[i][j][reg] + bv;
      }
    }
  }
}

// ---------------------------------------------------------------------------
// Fallback prepasses (linear layouts) for non-256-divisible shapes.
// ---------------------------------------------------------------------------
__global__ __launch_bounds__(256) void dequant_kernel(
    const int* __restrict__ qweight, const int* __restrict__ qzeros,
    const float* __restrict__ scales, short* __restrict__ Wt,
    int in_f, int out_f) {
  __shared__ __align__(16) short T[64][72];
  const int n0 = blockIdx.x * 64;
  const int k0 = blockIdx.y * 64;
  const int t = threadIdx.x;
  const int nl = t & 63;
  const int kw = t >> 6;
  const int n = n0 + nl;
  const int g = k0 >> 7;
  const float sc = scales[(size_t)g * out_f + n];
  const int zpw = qzeros[(size_t)g * (out_f >> 3) + (n >> 3)];
  const float zp = (float)(((zpw >> ((n & 7) * 4)) & 15) + 1);
  const float zs = zp * sc;
#pragma unroll
  for (int rr = 0; rr < 2; ++rr) {
    const int kwi = kw + rr * 4;
    const int w = qweight[(size_t)((k0 >> 3) + kwi) * out_f + n];
    short8 v;
#pragma unroll
    for (int e = 0; e < 8; ++e) {
      float f = (float)((w >> (4 * e)) & 15) * sc - zs;
      v[e] = f2bf(f);
    }
    *(short8*)&T[nl][kwi * 8] = v;
  }
  __syncthreads();
#pragma unroll
  for (int rr = 0; rr < 2; ++rr) {
    const int c = rr * 256 + t;
    const int row = c >> 3, ch = c & 7;
    *(short8*)&Wt[(size_t)(n0 + row) * in_f + k0 + ch * 8] =
        *(const short8*)&T[row][ch * 8];
  }
}

__global__ __launch_bounds__(256) void cvt_kernel(
    const float* __restrict__ x, short* __restrict__ xb, long n8) {
  long i = (long)blockIdx.x * blockDim.x + threadIdx.x;
  if (i >= n8) return;
  const float* src = x + i * 8;
  float4 a = *(const float4*)src;
  float4 b = *(const float4*)(src + 4);
  short8 v;
  v[0] = f2bf(a.x); v[1] = f2bf(a.y); v[2] = f2bf(a.z); v[3] = f2bf(a.w);
  v[4] = f2bf(b.x); v[5] = f2bf(b.y); v[6] = f2bf(b.z); v[7] = f2bf(b.w);
  *(short8*)(xb + i * 8) = v;
}

// ---------------------------------------------------------------------------
// 128x128x64 GEMM (fallback for non-256-divisible shapes).
// ---------------------------------------------------------------------------
#define BM 128
#define BN 128
#define BK 64

template <bool A_BF16>
__global__ __launch_bounds__(256) void gemm_bias_kernel(
    const void* __restrict__ Av, const short* __restrict__ Bt,
    const float* __restrict__ bias, float* __restrict__ C,
    int M, int N, int K) {
  __shared__ __align__(16) short As[BM * BK];
  __shared__ __align__(16) short Bs[BN * BK];
  const int tid = threadIdx.x;
  const int bm = blockIdx.y * BM;
  const int bn = blockIdx.x * BN;
  const int wid = tid >> 6, lane = tid & 63;
  const int wr = wid >> 1, wc = wid & 1;
  const int lrow = lane & 15;
  const int lk = (lane >> 4) * 8;

  f32x4 acc[4][4] = {};

  for (int kt = 0; kt < K; kt += BK) {
    if constexpr (A_BF16) {
      const short* A = (const short*)Av;
#pragma unroll
      for (int r = 0; r < 4; ++r) {
        const int c = r * 256 + tid;
        const int row = c >> 3, ch = c & 7;
        gload_lds16(A + (size_t)(bm + row) * K + kt + ch * 8,
                    (char*)As + c * 16);
      }
    } else {
      const float* A = (const float*)Av;
#pragma unroll
      for (int r = 0; r < 4; ++r) {
        const int c = r * 256 + tid;
        const int row = c >> 3, ch = c & 7;
        const float* src = A + (size_t)(bm + row) * K + kt + ch * 8;
        float4 f0 = *(const float4*)src;
        float4 f1 = *(const float4*)(src + 4);
        short8 v;
        v[0] = f2bf(f0.x); v[1] = f2bf(f0.y); v[2] = f2bf(f0.z); v[3] = f2bf(f0.w);
        v[4] = f2bf(f1.x); v[5] = f2bf(f1.y); v[6] = f2bf(f1.z); v[7] = f2bf(f1.w);
        *(short8*)((char*)As + c * 16) = v;
      }
    }
#pragma unroll
    for (int r = 0; r < 4; ++r) {
      const int c = r * 256 + tid;
      const int row = c >> 3, ch = c & 7;
      gload_lds16(Bt + (size_t)(bn + row) * K + kt + ch * 8,
                  (char*)Bs + c * 16);
    }
    __syncthreads();
#pragma unroll
    for (int kk = 0; kk < 2; ++kk) {
      short8 af[4], bf[4];
#pragma unroll
      for (int i = 0; i < 4; ++i)
        af[i] = *(const short8*)&As[(wr * 64 + i * 16 + lrow) * BK + kk * 32 + lk];
#pragma unroll
      for (int j = 0; j < 4; ++j)
        bf[j] = *(const short8*)&Bs[(wc * 64 + j * 16 + lrow) * BK + kk * 32 + lk];
#pragma unroll
      for (int i = 0; i < 4; ++i)
#pragma unroll
        for (int j = 0; j < 4; ++j)
          acc[i][j] = __builtin_amdgcn_mfma_f32_16x16x32_bf16(
              af[i], bf[j], acc[i][j], 0, 0, 0);
    }
    __syncthreads();
  }

  const int crow0 = bm + wr * 64 + (lane >> 4) * 4;
  const int ccol0 = bn + wc * 64 + (lane & 15);
#pragma unroll
  for (int j = 0; j < 4; ++j) {
    const float bv = bias[ccol0 + j * 16];
#pragma unroll
    for (int i = 0; i < 4; ++i) {
#pragma unroll
      for (int r = 0; r < 4; ++r) {
        C[(size_t)(crow0 + i * 16 + r) * N + ccol0 + j * 16] = acc[i][j][r] + bv;
      }
    }
  }
}

// ---------------------------------------------------------------------------
// Last-resort fallback: naive fused dequant GEMM.
// ---------------------------------------------------------------------------
__global__ __launch_bounds__(256) void naive_kernel(
    const float* __restrict__ x, const float* __restrict__ scales,
    const float* __restrict__ bias, const int* __restrict__ qw,
    const int* __restrict__ qz, float* __restrict__ out,
    int M, int K, int N) {
  long idx = (long)blockIdx.x * blockDim.x + threadIdx.x;
  if (idx >= (long)M * N) return;
  const int n = (int)(idx % N);
  const int m = (int)(idx / N);
  float acc = 0.f;
  for (int g = 0; g < K / 128; ++g) {
    const float sc = scales[(size_t)g * N + n];
    const float zp =
        (float)(((qz[(size_t)g * (N >> 3) + (n >> 3)] >> ((n & 7) * 4)) & 15) + 1);
    const float zs = zp * sc;
    for (int kw = 0; kw < 16; ++kw) {
      const int w = qw[(size_t)(g * 16 + kw) * N + n];
      const float* xp = &x[(size_t)m * K + g * 128 + kw * 8];
#pragma unroll
      for (int e = 0; e < 8; ++e)
        acc += xp[e] * ((float)((w >> (4 * e)) & 15) * sc - zs);
    }
  }
  out[idx] = acc + bias[n];
}

// ---------------------------------------------------------------------------
extern "C" void kernel_launch(void* const* d_in, const int* in_sizes, int n_in,
                              void* d_out, int out_size, void* d_ws,
                              size_t ws_size, hipStream_t stream) {
  const float* x = (const float*)d_in[0];
  const float* scales = (const float*)d_in[1];
  const float* bias = (const float*)d_in[2];
  const int* qweight = (const int*)d_in[3];
  const int* qzeros = (const int*)d_in[4];
  float* out = (float*)d_out;

  const int out_f = in_sizes[2];            // 12288
  const int kwords = in_sizes[3] / out_f;   // 512
  const int in_f = kwords * 8;              // 4096
  const int tokens = in_sizes[0] / in_f;    // 8192
  const int M = tokens, K = in_f, N = out_f;

  const size_t wt_bytes = (size_t)K * N * sizeof(short);
  const size_t xb_bytes = (size_t)M * K * sizeof(short);

  const bool div128 = (M % BM == 0) && (N % BN == 0) && (K % BK == 0) &&
                      (K % 128 == 0) && (N % 64 == 0);
  const bool div256 = (M % GBM == 0) && (N % GBN == 0) && (K % 256 == 0);

  if (div256 && ws_size >= wt_bytes + xb_bytes) {
    // R12 pre-tiled path
    short* Btile = (short*)d_ws;                        // B' fragment tiles
    short* Atile = (short*)((char*)d_ws + wt_bytes);    // A' fragment tiles
    const int kt = K >> 5;
    dequant_tile_kernel<<<(N / 256) * kt, 256, 0, stream>>>(
        qweight, qzeros, scales, Btile, N, K);
    cvt_tile_kernel<<<(M / 256) * kt, 256, 0, stream>>>(x, Atile, K);
    gemm256_kernel<<<(M / GBM) * (N / GBN), 512, 0, stream>>>(
        Atile, Btile, bias, out, M, N, K);
  } else if (div128 && ws_size >= wt_bytes + xb_bytes) {
    short* Wt = (short*)d_ws;
    short* xb = (short*)((char*)d_ws + wt_bytes);
    dequant_kernel<<<dim3(N / 64, K / 64), 256, 0, stream>>>(
        qweight, qzeros, scales, Wt, K, N);
    const long n8 = (long)M * K / 8;
    cvt_kernel<<<(int)((n8 + 255) / 256), 256, 0, stream>>>(x, xb, n8);
    gemm_bias_kernel<true><<<dim3(N / BN, M / BM), 256, 0, stream>>>(
        xb, Wt, bias, out, M, N, K);
  } else if (div128 && ws_size >= wt_bytes) {
    short* Wt = (short*)d_ws;
    dequant_kernel<<<dim3(N / 64, K / 64), 256, 0, stream>>>(
        qweight, qzeros, scales, Wt, K, N);
    gemm_bias_kernel<false><<<dim3(N / BN, M / BM), 256, 0, stream>>>(
        x, Wt, bias, out, M, N, K);
  } else {
    const long total = (long)M * N;
    naive_kernel<<<(int)((total + 255) / 256), 256, 0, stream>>>(
        x, scales, bias, qweight, qzeros, out, M, K, N);
  }
}

// Round 13
// 820.740 us; speedup vs baseline: 1.0276x; 1.0276x over previous
//
#include <hip/hip_runtime.h>
#include <hip/hip_bf16.h>

// ---------------------------------------------------------------------------
// WeightOnlyLinear: y = x @ dequant4(qweight, scales, qzeros) + bias
//   x (8192,4096) fp32 | scales (32,12288) | bias (12288) | qweight (512,12288)
//   qzeros (32,1536) | out (8192,12288) fp32
// R13: R10 (pre-tiled fragment-major operands, 32x32x16 MFMA, ring-4 K-half
//      slots, x4-unrolled) with m201-style DUAL-BARRIER phases:
//      {12 ds_reads(slot q) || stage(q+3) -> barA -> 16 MFMA -> vm8 -> barB}.
//      ds_read latency hides under barrier-arrival skew instead of stalling
//      the MFMA cluster head. Ledger: barB(q-1) confirms slot q DMA (vm8
//      leaves stages q-1,q-2; q-3's = slot q done) and read-retirement of
//      slot (q-1) -> stage target (q+3)&3 == (q-1)&3 safe. Tail 8/4/0/-.
// ---------------------------------------------------------------------------

typedef __attribute__((ext_vector_type(8))) short short8;
typedef __attribute__((ext_vector_type(4))) float f32x4;
typedef __attribute__((ext_vector_type(16))) float f32x16;

__device__ __forceinline__ short f2bf(float f) {
  unsigned u = __float_as_uint(f);
  u += 0x7fffu + ((u >> 16) & 1u);
  return (short)(u >> 16);
}

__device__ __forceinline__ void gload_lds16(const void* g, void* l) {
  __builtin_amdgcn_global_load_lds(
      (const __attribute__((address_space(1))) void*)g,
      (__attribute__((address_space(3))) void*)l,
      16, 0, 0);
}

__device__ __forceinline__ void bar() {
  asm volatile("" ::: "memory");
  __builtin_amdgcn_s_barrier();
  asm volatile("" ::: "memory");
}
__device__ __forceinline__ void wait_vm8() {
  asm volatile("s_waitcnt vmcnt(8)" ::: "memory");
}
__device__ __forceinline__ void wait_vm4() {
  asm volatile("s_waitcnt vmcnt(4)" ::: "memory");
}
__device__ __forceinline__ void wait_vm0() {
  asm volatile("s_waitcnt vmcnt(0)" ::: "memory");
}

// ---------------------------------------------------------------------------
// Pass 1: dequant qweight -> B' fragment-major tiles.
// Tile (nb256, h32) = 16KB; chunk c = cb*128 + kh*64 + kq2*32 + lane31.
// ---------------------------------------------------------------------------
__global__ __launch_bounds__(256) void dequant_tile_kernel(
    const int* __restrict__ qweight, const int* __restrict__ qzeros,
    const float* __restrict__ scales, short* __restrict__ Bt,
    int N, int K) {
  const int kt = K >> 5;
  const int bx = blockIdx.x;
  const int nb = bx / kt, h = bx - nb * kt;
  const int t = threadIdx.x;
  const int n = nb * 256 + t;
  const int g = h >> 2;
  const float sc = scales[(size_t)g * N + n];
  const int zw = qzeros[(size_t)g * (N >> 3) + (n >> 3)];
  const float zs = -(float)(((zw >> ((n & 7) * 4)) & 15) + 1) * sc;
  char* dst = (char*)Bt + (size_t)bx * 16384;
#pragma unroll
  for (int kw = 0; kw < 4; ++kw) {
    const int w = qweight[(size_t)(h * 4 + kw) * N + n];
    short8 v;
#pragma unroll
    for (int e = 0; e < 8; ++e)
      v[e] = f2bf(fmaf((float)((w >> (4 * e)) & 15), sc, zs));
    const int c = ((t >> 5) << 7) + ((kw >> 1) << 6) + ((kw & 1) << 5) + (t & 31);
    *(short8*)(dst + c * 16) = v;
  }
}

// ---------------------------------------------------------------------------
// Pass 2: x fp32 -> A' fragment-major tiles (same chunk mapping).
// ---------------------------------------------------------------------------
__global__ __launch_bounds__(256) void cvt_tile_kernel(
    const float* __restrict__ x, short* __restrict__ xb, int K) {
  const int kt = K >> 5;
  const int bx = blockIdx.x;
  const int mb = bx / kt, h = bx - mb * kt;
  const float* xs = x + (size_t)mb * 256 * K + h * 32;
  char* dst = (char*)xb + (size_t)bx * 16384;
#pragma unroll
  for (int p = 0; p < 4; ++p) {
    const int t2 = p * 256 + threadIdx.x;
    const int row = t2 >> 2, kq = t2 & 3;
    const float* s = xs + (size_t)row * K + kq * 8;
    float4 f0 = *(const float4*)s;
    float4 f1 = *(const float4*)(s + 4);
    short8 v;
    v[0] = f2bf(f0.x); v[1] = f2bf(f0.y); v[2] = f2bf(f0.z); v[3] = f2bf(f0.w);
    v[4] = f2bf(f1.x); v[5] = f2bf(f1.y); v[6] = f2bf(f1.z); v[7] = f2bf(f1.w);
    const int c = ((row >> 5) << 7) + ((kq >> 1) << 6) + ((kq & 1) << 5) + (row & 31);
    *(short8*)(dst + c * 16) = v;
  }
}

// ---------------------------------------------------------------------------
// Pass 3 (R13): 256x256 GEMM, 512 threads = 8 waves (2M x 4N), wave 128x64.
// MFMA 32x32x16; wave tile 4x2 frags of 32x32.
// LDS ring: 4 slots x 32KB, fragment-major (A 16KB @0, B 16KB @16384).
// Phase q (slot SL=q&3): 12x ds_read_b128 (a[4][2], b[2][2]) + stage(q+3)
//   [4 gload_lds] -> barA -> setprio/16 MFMA/setprio -> vmcnt tail -> barB.
// ---------------------------------------------------------------------------
#define GBM 256
#define GBN 256

__global__ __launch_bounds__(512, 2) void gemm256_kernel(
    const short* __restrict__ At, const short* __restrict__ Bt,
    const float* __restrict__ bias, float* __restrict__ C,
    int M, int N, int K) {
  __shared__ __align__(16) char lds[4][32768];
  const int tid = threadIdx.x;
  const int nbx = N / GBN;
  const int nwg = gridDim.x;
  int bid = blockIdx.x;
  if ((nwg & 7) == 0) bid = (bid & 7) * (nwg >> 3) + (bid >> 3);  // T1
  const int mb = bid / nbx;
  const int nb = bid % nbx;
  const int bm = mb * GBM, bn = nb * GBN;

  const int wid = tid >> 6, lane = tid & 63;
  const int wr = wid >> 2, wc = wid & 3;  // 2x4 wave grid
  const int l31 = lane & 31;
  const int lq2 = lane >> 5;

  const int P = K >> 5;  // K-halves; P % 4 == 0, P >= 8 (K % 256 == 0)

  char* lb = &lds[0][0];

  // ds_read base pointers [hi = slot>>1]; (slot&1)*32768 + i*2048 + kh*1024
  // are immediates.
  const char* aB[2];
  const char* bB[2];
  aB[0] = lb + wr * 8192 + lane * 16;          // rb = wr*4 + i
  aB[1] = aB[0] + 65536;
  bB[0] = lb + 16384 + wc * 4096 + lane * 16;  // cb = wc*2 + j
  bB[1] = bB[0] + 65536;

  // staging: pre-tiled sources, contiguous per K-half (16KB each)
  const char* gA = (const char*)At + (size_t)mb * P * 16384;
  const char* gB = (const char*)Bt + (size_t)nb * P * 16384;
  char* dstA0 = lb + tid * 16;
  char* dstA1 = dstA0 + 8192;
  char* dstB0 = dstA0 + 16384;
  char* dstB1 = dstA0 + 24576;
  const size_t t16 = (size_t)tid * 16;

#define STAGE(NSL, ASRC, BSRC)                               \
  do {                                                       \
    gload_lds16((ASRC) + t16, dstA0 + (NSL) * 32768);        \
    gload_lds16((ASRC) + t16 + 8192, dstA1 + (NSL) * 32768); \
    gload_lds16((BSRC) + t16, dstB0 + (NSL) * 32768);        \
    gload_lds16((BSRC) + t16 + 8192, dstB1 + (NSL) * 32768); \
  } while (0)

  f32x16 acc[4][2] = {};

  // Phase: reads+stage BEFORE barA (latency hides in barrier skew), MFMA
  // cluster after; vmcnt tail + barB establish next phase's preconditions.
#define PHASE(SL, ST, TW)                                                     \
  do {                                                                        \
    short8 a[4][2], b[2][2];                                                  \
    _Pragma("unroll") for (int i = 0; i < 4; ++i)                             \
        _Pragma("unroll") for (int kh = 0; kh < 2; ++kh) a[i][kh] =           \
        *(const short8*)(aB[(SL) >> 1] + ((SL)&1) * 32768 + i * 2048 +        \
                         kh * 1024);                                          \
    _Pragma("unroll") for (int j = 0; j < 2; ++j)                             \
        _Pragma("unroll") for (int kh = 0; kh < 2; ++kh) b[j][kh] =           \
        *(const short8*)(bB[(SL) >> 1] + ((SL)&1) * 32768 + j * 2048 +        \
                         kh * 1024);                                          \
    if (ST) STAGE(((SL) + 3) & 3, pA + (SL) * 16384, pB + (SL) * 16384);      \
    bar();                                                                    \
    __builtin_amdgcn_s_setprio(1);                                            \
    _Pragma("unroll") for (int kh = 0; kh < 2; ++kh)                          \
        _Pragma("unroll") for (int i = 0; i < 4; ++i)                         \
        _Pragma("unroll") for (int j = 0; j < 2; ++j) acc[i][j] =             \
            __builtin_amdgcn_mfma_f32_32x32x16_bf16(a[i][kh], b[j][kh],       \
                                                    acc[i][j], 0, 0, 0);      \
    __builtin_amdgcn_s_setprio(0);                                            \
    TW;                                                                       \
    bar();                                                                    \
  } while (0)

  // prologue: stage K-halves 0,1,2 into slots 0,1,2 (12 loads); slot 0
  // landed at vm8; bar -> phase 0 may read slot 0.
  STAGE(0, gA, gB);
  STAGE(1, gA + 16384, gB + 16384);
  STAGE(2, gA + 32768, gB + 32768);
  wait_vm8();
  bar();

  // main loop: PHASE(SL) stages K-half (4it+3+SL); end-wait vm8 confirms the
  // slot needed by the NEXT phase (stage issued 3 phases earlier).
  const char* pA = gA + 3 * 16384;
  const char* pB = gB + 3 * 16384;
  const int nIt = P / 4 - 1;
  for (int it = 0; it < nIt; ++it) {
    PHASE(0, true, wait_vm8());
    PHASE(1, true, wait_vm8());
    PHASE(2, true, wait_vm8());
    PHASE(3, true, wait_vm8());
    pA += 65536;
    pB += 65536;
  }
  // tail: phase P-4 stages K-half P-1; then drain 4/0/none.
  PHASE(0, true, wait_vm8());
  PHASE(1, false, wait_vm4());
  PHASE(2, false, wait_vm0());
  PHASE(3, false, (void)0);

#undef PHASE
#undef STAGE

  // epilogue: C = acc + bias.
  // 32x32 C/D map: col = lane&31, row = (reg&3) + 8*(reg>>2) + 4*(lane>>5)
  const int crow0 = bm + wr * 128 + 4 * lq2;
#pragma unroll
  for (int j = 0; j < 2; ++j) {
    const int ccol = bn + wc * 64 + j * 32 + l31;
    const float bv = bias[ccol];
#pragma unroll
    for (int i = 0; i < 4; ++i) {
#pragma unroll
      for (int reg = 0; reg < 16; ++reg) {
        const int row = crow0 + i * 32 + (reg & 3) + 8 * (reg >> 2);
        C[(size_t)row * N + ccol] = acc[i][j][reg] + bv;
      }
    }
  }
}

// ---------------------------------------------------------------------------
// Fallback prepasses (linear layouts) for non-256-divisible shapes.
// ---------------------------------------------------------------------------
__global__ __launch_bounds__(256) void dequant_kernel(
    const int* __restrict__ qweight, const int* __restrict__ qzeros,
    const float* __restrict__ scales, short* __restrict__ Wt,
    int in_f, int out_f) {
  __shared__ __align__(16) short T[64][72];
  const int n0 = blockIdx.x * 64;
  const int k0 = blockIdx.y * 64;
  const int t = threadIdx.x;
  const int nl = t & 63;
  const int kw = t >> 6;
  const int n = n0 + nl;
  const int g = k0 >> 7;
  const float sc = scales[(size_t)g * out_f + n];
  const int zpw = qzeros[(size_t)g * (out_f >> 3) + (n >> 3)];
  const float zp = (float)(((zpw >> ((n & 7) * 4)) & 15) + 1);
  const float zs = zp * sc;
#pragma unroll
  for (int rr = 0; rr < 2; ++rr) {
    const int kwi = kw + rr * 4;
    const int w = qweight[(size_t)((k0 >> 3) + kwi) * out_f + n];
    short8 v;
#pragma unroll
    for (int e = 0; e < 8; ++e) {
      float f = (float)((w >> (4 * e)) & 15) * sc - zs;
      v[e] = f2bf(f);
    }
    *(short8*)&T[nl][kwi * 8] = v;
  }
  __syncthreads();
#pragma unroll
  for (int rr = 0; rr < 2; ++rr) {
    const int c = rr * 256 + t;
    const int row = c >> 3, ch = c & 7;
    *(short8*)&Wt[(size_t)(n0 + row) * in_f + k0 + ch * 8] =
        *(const short8*)&T[row][ch * 8];
  }
}

__global__ __launch_bounds__(256) void cvt_kernel(
    const float* __restrict__ x, short* __restrict__ xb, long n8) {
  long i = (long)blockIdx.x * blockDim.x + threadIdx.x;
  if (i >= n8) return;
  const float* src = x + i * 8;
  float4 a = *(const float4*)src;
  float4 b = *(const float4*)(src + 4);
  short8 v;
  v[0] = f2bf(a.x); v[1] = f2bf(a.y); v[2] = f2bf(a.z); v[3] = f2bf(a.w);
  v[4] = f2bf(b.x); v[5] = f2bf(b.y); v[6] = f2bf(b.z); v[7] = f2bf(b.w);
  *(short8*)(xb + i * 8) = v;
}

// ---------------------------------------------------------------------------
// 128x128x64 GEMM (fallback for non-256-divisible shapes).
// ---------------------------------------------------------------------------
#define BM 128
#define BN 128
#define BK 64

template <bool A_BF16>
__global__ __launch_bounds__(256) void gemm_bias_kernel(
    const void* __restrict__ Av, const short* __restrict__ Bt,
    const float* __restrict__ bias, float* __restrict__ C,
    int M, int N, int K) {
  __shared__ __align__(16) short As[BM * BK];
  __shared__ __align__(16) short Bs[BN * BK];
  const int tid = threadIdx.x;
  const int bm = blockIdx.y * BM;
  const int bn = blockIdx.x * BN;
  const int wid = tid >> 6, lane = tid & 63;
  const int wr = wid >> 1, wc = wid & 1;
  const int lrow = lane & 15;
  const int lk = (lane >> 4) * 8;

  f32x4 acc[4][4] = {};

  for (int kt = 0; kt < K; kt += BK) {
    if constexpr (A_BF16) {
      const short* A = (const short*)Av;
#pragma unroll
      for (int r = 0; r < 4; ++r) {
        const int c = r * 256 + tid;
        const int row = c >> 3, ch = c & 7;
        gload_lds16(A + (size_t)(bm + row) * K + kt + ch * 8,
                    (char*)As + c * 16);
      }
    } else {
      const float* A = (const float*)Av;
#pragma unroll
      for (int r = 0; r < 4; ++r) {
        const int c = r * 256 + tid;
        const int row = c >> 3, ch = c & 7;
        const float* src = A + (size_t)(bm + row) * K + kt + ch * 8;
        float4 f0 = *(const float4*)src;
        float4 f1 = *(const float4*)(src + 4);
        short8 v;
        v[0] = f2bf(f0.x); v[1] = f2bf(f0.y); v[2] = f2bf(f0.z); v[3] = f2bf(f0.w);
        v[4] = f2bf(f1.x); v[5] = f2bf(f1.y); v[6] = f2bf(f1.z); v[7] = f2bf(f1.w);
        *(short8*)((char*)As + c * 16) = v;
      }
    }
#pragma unroll
    for (int r = 0; r < 4; ++r) {
      const int c = r * 256 + tid;
      const int row = c >> 3, ch = c & 7;
      gload_lds16(Bt + (size_t)(bn + row) * K + kt + ch * 8,
                  (char*)Bs + c * 16);
    }
    __syncthreads();
#pragma unroll
    for (int kk = 0; kk < 2; ++kk) {
      short8 af[4], bf[4];
#pragma unroll
      for (int i = 0; i < 4; ++i)
        af[i] = *(const short8*)&As[(wr * 64 + i * 16 + lrow) * BK + kk * 32 + lk];
#pragma unroll
      for (int j = 0; j < 4; ++j)
        bf[j] = *(const short8*)&Bs[(wc * 64 + j * 16 + lrow) * BK + kk * 32 + lk];
#pragma unroll
      for (int i = 0; i < 4; ++i)
#pragma unroll
        for (int j = 0; j < 4; ++j)
          acc[i][j] = __builtin_amdgcn_mfma_f32_16x16x32_bf16(
              af[i], bf[j], acc[i][j], 0, 0, 0);
    }
    __syncthreads();
  }

  const int crow0 = bm + wr * 64 + (lane >> 4) * 4;
  const int ccol0 = bn + wc * 64 + (lane & 15);
#pragma unroll
  for (int j = 0; j < 4; ++j) {
    const float bv = bias[ccol0 + j * 16];
#pragma unroll
    for (int i = 0; i < 4; ++i) {
#pragma unroll
      for (int r = 0; r < 4; ++r) {
        C[(size_t)(crow0 + i * 16 + r) * N + ccol0 + j * 16] = acc[i][j][r] + bv;
      }
    }
  }
}

// ---------------------------------------------------------------------------
// Last-resort fallback: naive fused dequant GEMM.
// ---------------------------------------------------------------------------
__global__ __launch_bounds__(256) void naive_kernel(
    const float* __restrict__ x, const float* __restrict__ scales,
    const float* __restrict__ bias, const int* __restrict__ qw,
    const int* __restrict__ qz, float* __restrict__ out,
    int M, int K, int N) {
  long idx = (long)blockIdx.x * blockDim.x + threadIdx.x;
  if (idx >= (long)M * N) return;
  const int n = (int)(idx % N);
  const int m = (int)(idx / N);
  float acc = 0.f;
  for (int g = 0; g < K / 128; ++g) {
    const float sc = scales[(size_t)g * N + n];
    const float zp =
        (float)(((qz[(size_t)g * (N >> 3) + (n >> 3)] >> ((n & 7) * 4)) & 15) + 1);
    const float zs = zp * sc;
    for (int kw = 0; kw < 16; ++kw) {
      const int w = qw[(size_t)(g * 16 + kw) * N + n];
      const float* xp = &x[(size_t)m * K + g * 128 + kw * 8];
#pragma unroll
      for (int e = 0; e < 8; ++e)
        acc += xp[e] * ((float)((w >> (4 * e)) & 15) * sc - zs);
    }
  }
  out[idx] = acc + bias[n];
}

// ---------------------------------------------------------------------------
extern "C" void kernel_launch(void* const* d_in, const int* in_sizes, int n_in,
                              void* d_out, int out_size, void* d_ws,
                              size_t ws_size, hipStream_t stream) {
  const float* x = (const float*)d_in[0];
  const float* scales = (const float*)d_in[1];
  const float* bias = (const float*)d_in[2];
  const int* qweight = (const int*)d_in[3];
  const int* qzeros = (const int*)d_in[4];
  float* out = (float*)d_out;

  const int out_f = in_sizes[2];            // 12288
  const int kwords = in_sizes[3] / out_f;   // 512
  const int in_f = kwords * 8;              // 4096
  const int tokens = in_sizes[0] / in_f;    // 8192
  const int M = tokens, K = in_f, N = out_f;

  const size_t wt_bytes = (size_t)K * N * sizeof(short);
  const size_t xb_bytes = (size_t)M * K * sizeof(short);

  const bool div128 = (M % BM == 0) && (N % BN == 0) && (K % BK == 0) &&
                      (K % 128 == 0) && (N % 64 == 0);
  const bool div256 = (M % GBM == 0) && (N % GBN == 0) && (K % 256 == 0);

  if (div256 && ws_size >= wt_bytes + xb_bytes) {
    // R13 pre-tiled path
    short* Btile = (short*)d_ws;                        // B' fragment tiles
    short* Atile = (short*)((char*)d_ws + wt_bytes);    // A' fragment tiles
    const int kt = K >> 5;
    dequant_tile_kernel<<<(N / 256) * kt, 256, 0, stream>>>(
        qweight, qzeros, scales, Btile, N, K);
    cvt_tile_kernel<<<(M / 256) * kt, 256, 0, stream>>>(x, Atile, K);
    gemm256_kernel<<<(M / GBM) * (N / GBN), 512, 0, stream>>>(
        Atile, Btile, bias, out, M, N, K);
  } else if (div128 && ws_size >= wt_bytes + xb_bytes) {
    short* Wt = (short*)d_ws;
    short* xb = (short*)((char*)d_ws + wt_bytes);
    dequant_kernel<<<dim3(N / 64, K / 64), 256, 0, stream>>>(
        qweight, qzeros, scales, Wt, K, N);
    const long n8 = (long)M * K / 8;
    cvt_kernel<<<(int)((n8 + 255) / 256), 256, 0, stream>>>(x, xb, n8);
    gemm_bias_kernel<true><<<dim3(N / BN, M / BM), 256, 0, stream>>>(
        xb, Wt, bias, out, M, N, K);
  } else if (div128 && ws_size >= wt_bytes) {
    short* Wt = (short*)d_ws;
    dequant_kernel<<<dim3(N / 64, K / 64), 256, 0, stream>>>(
        qweight, qzeros, scales, Wt, K, N);
    gemm_bias_kernel<false><<<dim3(N / BN, M / BM), 256, 0, stream>>>(
        x, Wt, bias, out, M, N, K);
  } else {
    const long total = (long)M * N;
    naive_kernel<<<(int)((total + 255) / 256), 256, 0, stream>>>(
        x, scales, bias, qweight, qzeros, out, M, K, N);
  }
}